// Round 1
// baseline (1108.330 us; speedup 1.0000x reference)
//
#include <hip/hip_runtime.h>

#define N_NODES 6000
#define DEG_    16
#define N_EDGES (N_NODES*DEG_)
#define D_MODEL 256
#define D_MSG   64
#define D_FF    1024

__device__ __forceinline__ float silu_f(float v) { return v / (1.0f + expf(-v)); }

// ---------------- embed: x[i] = emb[an[i]] ----------------
__global__ __launch_bounds__(256) void embed_kernel(const int* __restrict__ an,
    const float* __restrict__ emb, float* __restrict__ x) {
    int i = blockIdx.x;
    int t = threadIdx.x;
    x[i*D_MODEL + t] = emb[an[i]*D_MODEL + t];
}

// ---------------- geometry: d = |r|, rhat = r/d (stored [E,4]) ----------------
__global__ __launch_bounds__(256) void geom_kernel(const float* __restrict__ r,
    float* __restrict__ d, float* __restrict__ rhat) {
    int e = blockIdx.x*256 + threadIdx.x;
    if (e >= N_EDGES) return;
    float x = r[e*3+0], y = r[e*3+1], z = r[e*3+2];
    float n = sqrtf(x*x + y*y + z*z);
    d[e] = n;
    float inv = 1.0f / n;
    float4 v = make_float4(x*inv, y*inv, z*inv, 0.f);
    *(float4*)(rhat + (size_t)e*4) = v;
}

// ---------------- generic tiled GEMM: C = act(A @ B^T + bias) ----------------
// A [M,K] lda ; B [N,K] ldb ; C [M,*] ldc ; N multiple of 64, K multiple of 16.
// RBF=1: A[m][k] = exp(-gamma*(d[m]-center_k)^2) computed on the fly from dvec.
template<int ACT, int RBF>
__global__ __launch_bounds__(256) void gemm_kernel(
    const float* __restrict__ A, int lda,
    const float* __restrict__ B, int ldb,
    const float* __restrict__ bias,
    float* __restrict__ C, int ldc,
    int M, int N, int K,
    const float* __restrict__ dvec) {
    __shared__ float As[16][64];
    __shared__ float Bs[16][64];
    int t  = threadIdx.x;
    int n0 = blockIdx.x * 64;
    int m0 = blockIdx.y * 64;
    int mr = t & 63;       // row within tile for staging loads
    int kq = t >> 6;       // 0..3 k-quad for staging
    int tm = t >> 4;       // 0..15 output row group
    int tn = t & 15;       // 0..15 output col group

    float acc[4][4] = {};
    float dval = 0.f;
    if (RBF) dval = (m0 + mr < M) ? dvec[m0 + mr] : 0.f;

    for (int k0 = 0; k0 < K; k0 += 16) {
        float4 av;
        if (RBF) {
            const float gamma = 31.875f;           // 1/(8/255)
            const float step  = 8.0f / 255.0f;
            int kb = k0 + kq*4;
            float t0 = dval - (kb+0)*step;
            float t1 = dval - (kb+1)*step;
            float t2 = dval - (kb+2)*step;
            float t3 = dval - (kb+3)*step;
            av.x = expf(-gamma * t0*t0);
            av.y = expf(-gamma * t1*t1);
            av.z = expf(-gamma * t2*t2);
            av.w = expf(-gamma * t3*t3);
        } else {
            int m = m0 + mr;
            av = (m < M) ? *(const float4*)(A + (size_t)m*lda + k0 + kq*4)
                         : make_float4(0.f,0.f,0.f,0.f);
        }
        float4 bv = *(const float4*)(B + (size_t)(n0 + mr)*ldb + k0 + kq*4);
        // staged transposed; per-wave kq uniform -> stride-1 LDS writes (conflict-free)
        As[kq*4+0][mr] = av.x; As[kq*4+1][mr] = av.y;
        As[kq*4+2][mr] = av.z; As[kq*4+3][mr] = av.w;
        Bs[kq*4+0][mr] = bv.x; Bs[kq*4+1][mr] = bv.y;
        Bs[kq*4+2][mr] = bv.z; Bs[kq*4+3][mr] = bv.w;
        __syncthreads();
        #pragma unroll
        for (int kk = 0; kk < 16; ++kk) {
            float4 a = *(const float4*)(&As[kk][tm*4]);
            float4 b = *(const float4*)(&Bs[kk][tn*4]);
            acc[0][0] += a.x*b.x; acc[0][1] += a.x*b.y; acc[0][2] += a.x*b.z; acc[0][3] += a.x*b.w;
            acc[1][0] += a.y*b.x; acc[1][1] += a.y*b.y; acc[1][2] += a.y*b.z; acc[1][3] += a.y*b.w;
            acc[2][0] += a.z*b.x; acc[2][1] += a.z*b.y; acc[2][2] += a.z*b.z; acc[2][3] += a.z*b.w;
            acc[3][0] += a.w*b.x; acc[3][1] += a.w*b.y; acc[3][2] += a.w*b.z; acc[3][3] += a.w*b.w;
        }
        __syncthreads();
    }
    float b0 = bias[n0 + tn*4 + 0];
    float b1 = bias[n0 + tn*4 + 1];
    float b2 = bias[n0 + tn*4 + 2];
    float b3 = bias[n0 + tn*4 + 3];
    #pragma unroll
    for (int i = 0; i < 4; ++i) {
        int m = m0 + tm*4 + i;
        if (m < M) {
            float4 o = make_float4(acc[i][0]+b0, acc[i][1]+b1, acc[i][2]+b2, acc[i][3]+b3);
            if (ACT) { o.x = silu_f(o.x); o.y = silu_f(o.y); o.z = silu_f(o.z); o.w = silu_f(o.w); }
            *(float4*)(C + (size_t)m*ldc + n0 + tn*4) = o;
        }
    }
}

// ---------------- angle attention, one block per node ----------------
// xij[p] = xj[src[e_p]] + xi[node] + eproj[e_p]  kept in LDS; z recomputed.
// xn[node] = sum_p w_p * xij[p],  w_p = sum_q softmax_p(logit[p][q])
__global__ __launch_bounds__(256) void angle_kernel(
    const float* __restrict__ xjxi,   // [N,128]: cols 0..63 = xj, 64..127 = xi
    const float* __restrict__ eproj,  // [E,192], pre-offset by l*64
    const float* __restrict__ rhat,   // [E,4]
    const int*   __restrict__ src,    // [E]
    const float* __restrict__ attn,   // [64] pre-offset
    float* __restrict__ xn) {         // [N,64]
    __shared__ float s_xij[16][64];
    __shared__ float s_rhat[16][4];
    __shared__ float s_theta[16][16];
    __shared__ float s_logit[16][16];
    __shared__ float s_a[16][16];
    __shared__ float s_w[16];
    __shared__ float s_attn[64];
    int node = blockIdx.x;
    int t = threadIdx.x;

    if (t < 64) s_attn[t] = attn[t];
    if (t < 16) {
        float4 rv = *(const float4*)(rhat + (size_t)(node*DEG_ + t)*4);
        s_rhat[t][0] = rv.x; s_rhat[t][1] = rv.y; s_rhat[t][2] = rv.z; s_rhat[t][3] = 0.f;
    }
    {
        int p = t >> 4, seg = t & 15;
        int e = node*DEG_ + p;
        int se = src[e];
        float4 a = *(const float4*)(xjxi + (size_t)se*128 + seg*4);
        float4 b = *(const float4*)(xjxi + (size_t)node*128 + 64 + seg*4);
        float4 c = *(const float4*)(eproj + (size_t)e*192 + seg*4);
        float4 v = make_float4(a.x+b.x+c.x, a.y+b.y+c.y, a.z+b.z+c.z, a.w+b.w+c.w);
        *(float4*)(&s_xij[p][seg*4]) = v;
    }
    __syncthreads();
    {
        int p = t >> 4, q = t & 15;
        float dt = s_rhat[p][0]*s_rhat[q][0] + s_rhat[p][1]*s_rhat[q][1] + s_rhat[p][2]*s_rhat[q][2];
        dt = fminf(fmaxf(dt, -0.999999f), 0.999999f);
        s_theta[p][q] = acosf(dt);
    }
    __syncthreads();
    {
        int w = t >> 6, lane = t & 63;
        float ak = s_attn[lane];
        for (int m = w; m < 240; m += 4) {
            int p  = m / 15;
            int qq = m - p*15;
            int q  = qq + (qq >= p ? 1 : 0);
            float th = s_theta[p][q];
            float z  = cosf((float)lane * th);        // Chebyshev T_k(cos) via cos(k*theta)
            float v  = z + s_xij[p][lane] + s_xij[q][lane];
            float e  = silu_f(v);
            float pr = e * ak;
            #pragma unroll
            for (int off = 32; off > 0; off >>= 1) pr += __shfl_xor(pr, off);
            if (lane == 0) s_logit[p][q] = pr;
        }
    }
    __syncthreads();
    if (t < 16) {                                     // softmax over p for each q
        int q = t;
        float mx = -1e30f;
        #pragma unroll
        for (int p = 0; p < 16; ++p) if (p != q) mx = fmaxf(mx, s_logit[p][q]);
        float ssum = 0.f;
        float ex[16];
        #pragma unroll
        for (int p = 0; p < 16; ++p) {
            float e = (p == q) ? 0.f : expf(s_logit[p][q] - mx);
            ex[p] = e; ssum += e;
        }
        float inv = 1.0f / ssum;
        #pragma unroll
        for (int p = 0; p < 16; ++p) s_a[p][q] = ex[p] * inv;
    }
    __syncthreads();
    if (t < 16) {
        int p = t;
        float sw = 0.f;
        #pragma unroll
        for (int q = 0; q < 16; ++q) sw += s_a[p][q];
        s_w[p] = sw;
    }
    __syncthreads();
    if (t < 64) {
        float acc = 0.f;
        #pragma unroll
        for (int p = 0; p < 16; ++p) acc += s_w[p] * s_xij[p][t];
        xn[(size_t)node*64 + t] = acc;
    }
}

// ---------------- final: out = bfc + mean_i (x[i] . Wfc) ----------------
__global__ void init_out(float* __restrict__ out, const float* __restrict__ bfc) {
    out[0] = bfc[0];
}
__global__ __launch_bounds__(256) void reduce_kernel(const float* __restrict__ x,
    const float* __restrict__ Wfc, float* __restrict__ out) {
    __shared__ float s[256];
    int t = threadIdx.x;
    float local = 0.f;
    for (int i = blockIdx.x; i < N_NODES; i += gridDim.x) local += x[(size_t)i*D_MODEL + t];
    local *= Wfc[t];
    s[t] = local; __syncthreads();
    for (int off = 128; off > 0; off >>= 1) {
        if (t < off) s[t] += s[t+off];
        __syncthreads();
    }
    if (t == 0) atomicAdd(out, s[0] * (1.0f/ (float)N_NODES));
}

extern "C" void kernel_launch(void* const* d_in, const int* in_sizes, int n_in,
                              void* d_out, int out_size, void* d_ws, size_t ws_size,
                              hipStream_t stream) {
    (void)in_sizes; (void)n_in; (void)out_size; (void)ws_size;
    const float* r    = (const float*)d_in[0];
    const int*   an   = (const int*)  d_in[1];
    const int*   src  = (const int*)  d_in[2];
    const float* emb  = (const float*)d_in[6];
    const float* Wsrc = (const float*)d_in[7];
    const float* bsrc = (const float*)d_in[8];
    const float* Wdst = (const float*)d_in[9];
    const float* bdst = (const float*)d_in[10];
    const float* Wedge= (const float*)d_in[11];
    const float* bedge= (const float*)d_in[12];
    const float* attn = (const float*)d_in[13];
    const float* W1   = (const float*)d_in[14];
    const float* b1   = (const float*)d_in[15];
    const float* W2   = (const float*)d_in[16];
    const float* b2   = (const float*)d_in[17];
    const float* Wfc  = (const float*)d_in[18];
    const float* bfc  = (const float*)d_in[19];

    float* ws = (float*)d_ws;
    float* d_d     = ws;                     // 96000
    float* d_rhat  = d_d + 96000;            // 384000
    float* d_eproj = d_rhat + 384000;        // 96000*192 = 18432000
    float* d_x     = d_eproj + 18432000;     // 1536000
    float* d_xjxi  = d_x + 1536000;          // 768000
    float* d_xn    = d_xjxi + 768000;        // 384000
    float* d_h     = d_xn + 384000;          // 6144000
    float* out = (float*)d_out;

    embed_kernel<<<N_NODES, 256, 0, stream>>>(an, emb, d_x);
    geom_kernel<<<(N_EDGES+255)/256, 256, 0, stream>>>(r, d_d, d_rhat);
    // eproj[e, l*64+m] for all 3 layers in one GEMM (Wedge flat is [192,256])
    gemm_kernel<0,1><<<dim3(3,1500), 256, 0, stream>>>(
        nullptr, 0, Wedge, 256, bedge, d_eproj, 192, N_EDGES, 192, 256, d_d);

    for (int l = 0; l < 3; ++l) {
        gemm_kernel<0,0><<<dim3(1,94), 256, 0, stream>>>(
            d_x, 256, Wsrc + (size_t)l*64*256, 256, bsrc + l*64,
            d_xjxi, 128, N_NODES, 64, 256, nullptr);
        gemm_kernel<0,0><<<dim3(1,94), 256, 0, stream>>>(
            d_x, 256, Wdst + (size_t)l*64*256, 256, bdst + l*64,
            d_xjxi + 64, 128, N_NODES, 64, 256, nullptr);
        angle_kernel<<<N_NODES, 256, 0, stream>>>(
            d_xjxi, d_eproj + l*64, d_rhat, src, attn + l*64, d_xn);
        gemm_kernel<1,0><<<dim3(16,94), 256, 0, stream>>>(
            d_xn, 64, W1 + (size_t)l*D_FF*64, 64, b1 + l*D_FF,
            d_h, D_FF, N_NODES, D_FF, 64, nullptr);
        gemm_kernel<0,0><<<dim3(4,94), 256, 0, stream>>>(
            d_h, D_FF, W2 + (size_t)l*D_MODEL*D_FF, D_FF, b2 + l*D_MODEL,
            d_x, D_MODEL, N_NODES, D_MODEL, D_FF, nullptr);
    }
    init_out<<<1, 1, 0, stream>>>(out, bfc);
    reduce_kernel<<<48, 256, 0, stream>>>(d_x, Wfc, out);
}

// Round 2
// 772.073 us; speedup vs baseline: 1.4355x; 1.4355x over previous
//
#include <hip/hip_runtime.h>

#define N_NODES 6000
#define DEG_    16
#define N_EDGES (N_NODES*DEG_)
#define D_MODEL 256
#define D_MSG   64
#define D_FF    1024

__device__ __forceinline__ float silu_f(float v) {
    return v * __builtin_amdgcn_rcpf(1.0f + __expf(-v));
}

// ---------------- embed: x[i] = emb[an[i]] ----------------
__global__ __launch_bounds__(256) void embed_kernel(const int* __restrict__ an,
    const float* __restrict__ emb, float* __restrict__ x) {
    int i = blockIdx.x;
    int t = threadIdx.x;
    x[i*D_MODEL + t] = emb[an[i]*D_MODEL + t];
}

// ---------------- geometry: d = |r|, rhat = r/d (stored [E,4]) ----------------
__global__ __launch_bounds__(256) void geom_kernel(const float* __restrict__ r,
    float* __restrict__ d, float* __restrict__ rhat) {
    int e = blockIdx.x*256 + threadIdx.x;
    if (e >= N_EDGES) return;
    float x = r[e*3+0], y = r[e*3+1], z = r[e*3+2];
    float n = sqrtf(x*x + y*y + z*z);
    d[e] = n;
    float inv = 1.0f / n;
    float4 v = make_float4(x*inv, y*inv, z*inv, 0.f);
    *(float4*)(rhat + (size_t)e*4) = v;
}

// ---------------- generic tiled GEMM: C = act(A @ B^T + bias) ----------------
template<int ACT, int RBF>
__global__ __launch_bounds__(256) void gemm_kernel(
    const float* __restrict__ A, int lda,
    const float* __restrict__ B, int ldb,
    const float* __restrict__ bias,
    float* __restrict__ C, int ldc,
    int M, int N, int K,
    const float* __restrict__ dvec) {
    __shared__ float As[16][64];
    __shared__ float Bs[16][64];
    int t  = threadIdx.x;
    int n0 = blockIdx.x * 64;
    int m0 = blockIdx.y * 64;
    int mr = t & 63;
    int kq = t >> 6;
    int tm = t >> 4;
    int tn = t & 15;

    float acc[4][4] = {};
    float dval = 0.f;
    if (RBF) dval = (m0 + mr < M) ? dvec[m0 + mr] : 0.f;

    for (int k0 = 0; k0 < K; k0 += 16) {
        float4 av;
        if (RBF) {
            const float gamma = 31.875f;
            const float step  = 8.0f / 255.0f;
            int kb = k0 + kq*4;
            float t0 = dval - (kb+0)*step;
            float t1 = dval - (kb+1)*step;
            float t2 = dval - (kb+2)*step;
            float t3 = dval - (kb+3)*step;
            av.x = __expf(-gamma * t0*t0);
            av.y = __expf(-gamma * t1*t1);
            av.z = __expf(-gamma * t2*t2);
            av.w = __expf(-gamma * t3*t3);
        } else {
            int m = m0 + mr;
            av = (m < M) ? *(const float4*)(A + (size_t)m*lda + k0 + kq*4)
                         : make_float4(0.f,0.f,0.f,0.f);
        }
        float4 bv = *(const float4*)(B + (size_t)(n0 + mr)*ldb + k0 + kq*4);
        As[kq*4+0][mr] = av.x; As[kq*4+1][mr] = av.y;
        As[kq*4+2][mr] = av.z; As[kq*4+3][mr] = av.w;
        Bs[kq*4+0][mr] = bv.x; Bs[kq*4+1][mr] = bv.y;
        Bs[kq*4+2][mr] = bv.z; Bs[kq*4+3][mr] = bv.w;
        __syncthreads();
        #pragma unroll
        for (int kk = 0; kk < 16; ++kk) {
            float4 a = *(const float4*)(&As[kk][tm*4]);
            float4 b = *(const float4*)(&Bs[kk][tn*4]);
            acc[0][0] += a.x*b.x; acc[0][1] += a.x*b.y; acc[0][2] += a.x*b.z; acc[0][3] += a.x*b.w;
            acc[1][0] += a.y*b.x; acc[1][1] += a.y*b.y; acc[1][2] += a.y*b.z; acc[1][3] += a.y*b.w;
            acc[2][0] += a.z*b.x; acc[2][1] += a.z*b.y; acc[2][2] += a.z*b.z; acc[2][3] += a.z*b.w;
            acc[3][0] += a.w*b.x; acc[3][1] += a.w*b.y; acc[3][2] += a.w*b.z; acc[3][3] += a.w*b.w;
        }
        __syncthreads();
    }
    float b0 = bias[n0 + tn*4 + 0];
    float b1 = bias[n0 + tn*4 + 1];
    float b2 = bias[n0 + tn*4 + 2];
    float b3 = bias[n0 + tn*4 + 3];
    #pragma unroll
    for (int i = 0; i < 4; ++i) {
        int m = m0 + tm*4 + i;
        if (m < M) {
            float4 o = make_float4(acc[i][0]+b0, acc[i][1]+b1, acc[i][2]+b2, acc[i][3]+b3);
            if (ACT) { o.x = silu_f(o.x); o.y = silu_f(o.y); o.z = silu_f(o.z); o.w = silu_f(o.w); }
            *(float4*)(C + (size_t)m*ldc + n0 + tn*4) = o;
        }
    }
}

// ---------------- angle attention, one block per node ----------------
// One thread per ordered pair (p,q), p!=q: serial 64-term reduction with
// Chebyshev recurrence T_k(c)=2c*T_{k-1}-T_{k-2} (z = T_k(clip(cos)) exactly,
// so no cosf/acosf at all). No cross-lane shuffles.
#define XSTRIDE 68   // 16B-aligned rows (68*4=272B), decorrelates banks
__global__ __launch_bounds__(256) void angle_kernel(
    const float* __restrict__ xjxi,   // [N,128]: cols 0..63 = xj, 64..127 = xi
    const float* __restrict__ eproj,  // [E,192], pre-offset by l*64
    const float* __restrict__ rhat,   // [E,4]
    const int*   __restrict__ src,    // [E]
    const float* __restrict__ attn,   // [64] pre-offset
    float* __restrict__ xn) {         // [N,64]
    __shared__ __align__(16) float s_xij[16][XSTRIDE];
    __shared__ __align__(16) float s_attn[64];
    __shared__ float s_rhat[16][4];
    __shared__ float s_c[16][17];
    __shared__ float s_logit[16][17];
    __shared__ float s_a[16][17];
    __shared__ float s_w[16];
    int node = blockIdx.x;
    int t = threadIdx.x;

    if (t < 64) s_attn[t] = attn[t];
    if (t < 16) {
        float4 rv = *(const float4*)(rhat + (size_t)(node*DEG_ + t)*4);
        s_rhat[t][0] = rv.x; s_rhat[t][1] = rv.y; s_rhat[t][2] = rv.z; s_rhat[t][3] = 0.f;
    }
    {
        int p = t >> 4, seg = t & 15;
        int e = node*DEG_ + p;
        int se = src[e];
        float4 a = *(const float4*)(xjxi + (size_t)se*128 + seg*4);
        float4 b = *(const float4*)(xjxi + (size_t)node*128 + 64 + seg*4);
        float4 c = *(const float4*)(eproj + (size_t)e*192 + seg*4);
        float4 v = make_float4(a.x+b.x+c.x, a.y+b.y+c.y, a.z+b.z+c.z, a.w+b.w+c.w);
        *(float4*)(&s_xij[p][seg*4]) = v;
    }
    __syncthreads();
    {
        int p = t >> 4, q = t & 15;
        float dt = s_rhat[p][0]*s_rhat[q][0] + s_rhat[p][1]*s_rhat[q][1] + s_rhat[p][2]*s_rhat[q][2];
        s_c[p][q] = fminf(fmaxf(dt, -0.999999f), 0.999999f);
    }
    __syncthreads();
    if (t < 240) {
        int p  = t / 15;
        int qq = t - p*15;
        int q  = qq + (qq >= p ? 1 : 0);
        float c   = s_c[p][q];
        float c2  = 2.0f * c;
        float tk0 = 1.0f;   // T_0
        float tk1 = c;      // T_1
        float acc = 0.f;
        const float* xp = &s_xij[p][0];
        const float* xq = &s_xij[q][0];
        #pragma unroll
        for (int k0 = 0; k0 < 64; k0 += 4) {
            float4 xp4 = *(const float4*)(xp + k0);
            float4 xq4 = *(const float4*)(xq + k0);
            float4 a4  = *(const float4*)(&s_attn[k0]);
            float v0 = tk0 + xp4.x + xq4.x;
            acc = fmaf(a4.x, silu_f(v0), acc);
            { float tn2 = c2*tk1 - tk0; tk0 = tk1; tk1 = tn2; }
            float v1 = tk0 + xp4.y + xq4.y;
            acc = fmaf(a4.y, silu_f(v1), acc);
            { float tn2 = c2*tk1 - tk0; tk0 = tk1; tk1 = tn2; }
            float v2 = tk0 + xp4.z + xq4.z;
            acc = fmaf(a4.z, silu_f(v2), acc);
            { float tn2 = c2*tk1 - tk0; tk0 = tk1; tk1 = tn2; }
            float v3 = tk0 + xp4.w + xq4.w;
            acc = fmaf(a4.w, silu_f(v3), acc);
            { float tn2 = c2*tk1 - tk0; tk0 = tk1; tk1 = tn2; }
        }
        s_logit[p][q] = acc;
    }
    __syncthreads();
    if (t < 16) {                                     // softmax over p for each q
        int q = t;
        float mx = -1e30f;
        #pragma unroll
        for (int p = 0; p < 16; ++p) if (p != q) mx = fmaxf(mx, s_logit[p][q]);
        float ssum = 0.f;
        float ex[16];
        #pragma unroll
        for (int p = 0; p < 16; ++p) {
            float e = (p == q) ? 0.f : __expf(s_logit[p][q] - mx);
            ex[p] = e; ssum += e;
        }
        float inv = 1.0f / ssum;
        #pragma unroll
        for (int p = 0; p < 16; ++p) s_a[p][q] = ex[p] * inv;
    }
    __syncthreads();
    if (t < 16) {
        int p = t;
        float sw = 0.f;
        #pragma unroll
        for (int q = 0; q < 16; ++q) sw += s_a[p][q];
        s_w[p] = sw;
    }
    __syncthreads();
    if (t < 64) {
        float acc = 0.f;
        #pragma unroll
        for (int p = 0; p < 16; ++p) acc += s_w[p] * s_xij[p][t];
        xn[(size_t)node*64 + t] = acc;
    }
}

// ---------------- final: out = bfc + mean_i (x[i] . Wfc) ----------------
__global__ void init_out(float* __restrict__ out, const float* __restrict__ bfc) {
    out[0] = bfc[0];
}
__global__ __launch_bounds__(256) void reduce_kernel(const float* __restrict__ x,
    const float* __restrict__ Wfc, float* __restrict__ out) {
    __shared__ float s[256];
    int t = threadIdx.x;
    float local = 0.f;
    for (int i = blockIdx.x; i < N_NODES; i += gridDim.x) local += x[(size_t)i*D_MODEL + t];
    local *= Wfc[t];
    s[t] = local; __syncthreads();
    for (int off = 128; off > 0; off >>= 1) {
        if (t < off) s[t] += s[t+off];
        __syncthreads();
    }
    if (t == 0) atomicAdd(out, s[0] * (1.0f/ (float)N_NODES));
}

extern "C" void kernel_launch(void* const* d_in, const int* in_sizes, int n_in,
                              void* d_out, int out_size, void* d_ws, size_t ws_size,
                              hipStream_t stream) {
    (void)in_sizes; (void)n_in; (void)out_size; (void)ws_size;
    const float* r    = (const float*)d_in[0];
    const int*   an   = (const int*)  d_in[1];
    const int*   src  = (const int*)  d_in[2];
    const float* emb  = (const float*)d_in[6];
    const float* Wsrc = (const float*)d_in[7];
    const float* bsrc = (const float*)d_in[8];
    const float* Wdst = (const float*)d_in[9];
    const float* bdst = (const float*)d_in[10];
    const float* Wedge= (const float*)d_in[11];
    const float* bedge= (const float*)d_in[12];
    const float* attn = (const float*)d_in[13];
    const float* W1   = (const float*)d_in[14];
    const float* b1   = (const float*)d_in[15];
    const float* W2   = (const float*)d_in[16];
    const float* b2   = (const float*)d_in[17];
    const float* Wfc  = (const float*)d_in[18];
    const float* bfc  = (const float*)d_in[19];

    float* ws = (float*)d_ws;
    float* d_d     = ws;                     // 96000
    float* d_rhat  = d_d + 96000;            // 384000
    float* d_eproj = d_rhat + 384000;        // 96000*192 = 18432000
    float* d_x     = d_eproj + 18432000;     // 1536000
    float* d_xjxi  = d_x + 1536000;          // 768000
    float* d_xn    = d_xjxi + 768000;        // 384000
    float* d_h     = d_xn + 384000;          // 6144000
    float* out = (float*)d_out;

    embed_kernel<<<N_NODES, 256, 0, stream>>>(an, emb, d_x);
    geom_kernel<<<(N_EDGES+255)/256, 256, 0, stream>>>(r, d_d, d_rhat);
    gemm_kernel<0,1><<<dim3(3,1500), 256, 0, stream>>>(
        nullptr, 0, Wedge, 256, bedge, d_eproj, 192, N_EDGES, 192, 256, d_d);

    for (int l = 0; l < 3; ++l) {
        gemm_kernel<0,0><<<dim3(1,94), 256, 0, stream>>>(
            d_x, 256, Wsrc + (size_t)l*64*256, 256, bsrc + l*64,
            d_xjxi, 128, N_NODES, 64, 256, nullptr);
        gemm_kernel<0,0><<<dim3(1,94), 256, 0, stream>>>(
            d_x, 256, Wdst + (size_t)l*64*256, 256, bdst + l*64,
            d_xjxi + 64, 128, N_NODES, 64, 256, nullptr);
        angle_kernel<<<N_NODES, 256, 0, stream>>>(
            d_xjxi, d_eproj + l*64, d_rhat, src, attn + l*64, d_xn);
        gemm_kernel<1,0><<<dim3(16,94), 256, 0, stream>>>(
            d_xn, 64, W1 + (size_t)l*D_FF*64, 64, b1 + l*D_FF,
            d_h, D_FF, N_NODES, D_FF, 64, nullptr);
        gemm_kernel<0,0><<<dim3(4,94), 256, 0, stream>>>(
            d_h, D_FF, W2 + (size_t)l*D_MODEL*D_FF, D_FF, b2 + l*D_MODEL,
            d_x, D_MODEL, N_NODES, D_MODEL, D_FF, nullptr);
    }
    init_out<<<1, 1, 0, stream>>>(out, bfc);
    reduce_kernel<<<48, 256, 0, stream>>>(d_x, Wfc, out);
}

// Round 3
// 422.558 us; speedup vs baseline: 2.6229x; 1.8271x over previous
//
#include <hip/hip_runtime.h>

#define N_NODES 6000
#define DEG_    16
#define N_EDGES (N_NODES*DEG_)
#define D_MODEL 256
#define D_MSG   64
#define D_FF    1024

typedef __bf16 bf16x8 __attribute__((ext_vector_type(8)));
typedef float floatx4 __attribute__((ext_vector_type(4)));

__device__ __forceinline__ float silu_f(float v) {
    return v * __builtin_amdgcn_rcpf(1.0f + __expf(-v));
}
__device__ __forceinline__ float b2f(unsigned short u) {
    union { unsigned int i; float f; } v; v.i = ((unsigned int)u) << 16; return v.f;
}
__device__ __forceinline__ unsigned short f2b(float f) {
    union { float f; unsigned int i; } v; v.f = f;
    unsigned int r = (v.i + 0x7FFFu + ((v.i >> 16) & 1u)) >> 16;
    return (unsigned short)r;
}

// ---------------- weight conversion fp32 -> bf16 (once per launch) ----------------
#define WSRC_OFF 0
#define WDST_OFF 49152
#define WEDGE_OFF 98304
#define W1_OFF 147456
#define W2_OFF 344064
#define WTOTAL 1130496
__global__ __launch_bounds__(256) void cvt_weights(
    const float* __restrict__ Wsrc, const float* __restrict__ Wdst,
    const float* __restrict__ Wedge, const float* __restrict__ W1,
    const float* __restrict__ W2, unsigned short* __restrict__ dst) {
    int i = blockIdx.x*256 + threadIdx.x;
    if (i >= WTOTAL) return;
    float v;
    if      (i < WDST_OFF)  v = Wsrc[i];
    else if (i < WEDGE_OFF) v = Wdst[i - WDST_OFF];
    else if (i < W1_OFF)    v = Wedge[i - WEDGE_OFF];
    else if (i < W2_OFF)    v = W1[i - W1_OFF];
    else                    v = W2[i - W2_OFF];
    dst[i] = f2b(v);
}

// ---------------- embed: x[i] = bf16(emb[an[i]]) ----------------
__global__ __launch_bounds__(256) void embed_kernel(const int* __restrict__ an,
    const float* __restrict__ emb, unsigned short* __restrict__ x) {
    int i = blockIdx.x;
    int t = threadIdx.x;
    x[i*D_MODEL + t] = f2b(emb[an[i]*D_MODEL + t]);
}

// ---------------- geometry ----------------
__global__ __launch_bounds__(256) void geom_kernel(const float* __restrict__ r,
    float* __restrict__ d, float* __restrict__ rhat) {
    int e = blockIdx.x*256 + threadIdx.x;
    if (e >= N_EDGES) return;
    float x = r[e*3+0], y = r[e*3+1], z = r[e*3+2];
    float n = sqrtf(x*x + y*y + z*z);
    d[e] = n;
    float inv = 1.0f / n;
    *(float4*)(rhat + (size_t)e*4) = make_float4(x*inv, y*inv, z*inv, 0.f);
}

// ---------------- MFMA bf16 GEMM: C = bf16(act(A @ B^T + bias)) ----------------
// Block tile 128x64, 4 waves each 32x64, BK=32, mfma_f32_16x16x32_bf16.
// A [M,K] bf16 (RBF=1: generated from dvec), B [N,K] bf16 row-major (= W),
// C [M,*] bf16. DUALB: grid.x==2, block col 0 -> B1/bias1, col 1 -> B2/bias2
// (each a 64-row matrix). Non-dual bias indexed by global col.
#define APITCH 40
template<int ACT, int RBF, int DUALB>
__global__ __launch_bounds__(256) void mgemm(
    const unsigned short* __restrict__ A, int lda,
    const unsigned short* __restrict__ B1, const unsigned short* __restrict__ B2, int ldb,
    const float* __restrict__ bias1, const float* __restrict__ bias2,
    unsigned short* __restrict__ C, int ldc, int M, int K,
    const float* __restrict__ dvec) {
    __shared__ __align__(16) unsigned short As[128*APITCH];
    __shared__ __align__(16) unsigned short Bs[64*APITCH];
    const int t = threadIdx.x;
    const int w = t >> 6;
    const int lane = t & 63;
    const int lr = lane & 15;
    const int lq = lane >> 4;
    const int n0 = blockIdx.x * 64;
    const int m0 = blockIdx.y * 128;
    const unsigned short* B = B1;
    const float* bias = bias1;
    if (DUALB && blockIdx.x == 1) { B = B2; bias = bias2; }
    const unsigned short* Brow = DUALB ? B : (B + (size_t)n0*ldb);

    floatx4 acc[2][4] = {};

    for (int k0 = 0; k0 < K; k0 += 32) {
        #pragma unroll
        for (int it = 0; it < 2; ++it) {
            int i = t + it*256;
            int row = i >> 2, chk = i & 3;
            int gm = m0 + row;
            uint4 val = make_uint4(0,0,0,0);
            if (RBF) {
                const float gamma = 31.875f;
                const float step  = 8.0f / 255.0f;
                float dv = dvec[gm];          // RBF path has M % 128 == 0
                int kb = k0 + chk*8;
                unsigned short h[8];
                #pragma unroll
                for (int j = 0; j < 8; ++j) {
                    float tt = dv - (float)(kb+j) * step;
                    h[j] = f2b(__expf(-gamma * tt * tt));
                }
                val = *(uint4*)h;
            } else if (gm < M) {
                val = *(const uint4*)(A + (size_t)gm*lda + k0 + chk*8);
            }
            *(uint4*)(&As[row*APITCH + chk*8]) = val;
        }
        {
            int row = t >> 2, chk = t & 3;
            uint4 val = *(const uint4*)(Brow + (size_t)row*ldb + k0 + chk*8);
            *(uint4*)(&Bs[row*APITCH + chk*8]) = val;
        }
        __syncthreads();
        bf16x8 af[2], bfr[4];
        af[0] = *(const bf16x8*)(&As[(w*32 +      lr)*APITCH + lq*8]);
        af[1] = *(const bf16x8*)(&As[(w*32 + 16 + lr)*APITCH + lq*8]);
        #pragma unroll
        for (int ns = 0; ns < 4; ++ns)
            bfr[ns] = *(const bf16x8*)(&Bs[(ns*16 + lr)*APITCH + lq*8]);
        #pragma unroll
        for (int ns = 0; ns < 4; ++ns) {
            acc[0][ns] = __builtin_amdgcn_mfma_f32_16x16x32_bf16(af[0], bfr[ns], acc[0][ns], 0,0,0);
            acc[1][ns] = __builtin_amdgcn_mfma_f32_16x16x32_bf16(af[1], bfr[ns], acc[1][ns], 0,0,0);
        }
        __syncthreads();
    }
    #pragma unroll
    for (int ns = 0; ns < 4; ++ns) {
        int bc = ns*16 + lr;
        float bv = bias[DUALB ? bc : (n0 + bc)];
        #pragma unroll
        for (int ms = 0; ms < 2; ++ms) {
            #pragma unroll
            for (int rg = 0; rg < 4; ++rg) {
                int gm = m0 + w*32 + ms*16 + lq*4 + rg;
                if (gm < M) {
                    float v = acc[ms][ns][rg] + bv;
                    if (ACT) v = silu_f(v);
                    C[(size_t)gm*ldc + n0 + bc] = f2b(v);
                }
            }
        }
    }
}

// ---------------- angle attention, one block per node (bf16 IO, fp32 math) ----------------
#define XSTRIDE 68
__global__ __launch_bounds__(256) void angle_kernel(
    const unsigned short* __restrict__ xjxi,   // [N,128] bf16: 0..63 xj, 64..127 xi
    const unsigned short* __restrict__ eproj,  // [E,192] bf16, pre-offset by l*64
    const float* __restrict__ rhat,            // [E,4]
    const int*   __restrict__ src,             // [E]
    const float* __restrict__ attn,            // [64] pre-offset
    unsigned short* __restrict__ xn) {         // [N,64] bf16
    __shared__ __align__(16) float s_xij[16][XSTRIDE];
    __shared__ __align__(16) float s_attn[64];
    __shared__ float s_rhat[16][4];
    __shared__ float s_c[16][17];
    __shared__ float s_logit[16][17];
    __shared__ float s_a[16][17];
    __shared__ float s_w[16];
    int node = blockIdx.x;
    int t = threadIdx.x;

    if (t < 64) s_attn[t] = attn[t];
    if (t < 16) {
        float4 rv = *(const float4*)(rhat + (size_t)(node*DEG_ + t)*4);
        s_rhat[t][0] = rv.x; s_rhat[t][1] = rv.y; s_rhat[t][2] = rv.z; s_rhat[t][3] = 0.f;
    }
    if (t < 128) {
        int p = t >> 3, c8 = t & 7;
        int e = node*DEG_ + p;
        int se = src[e];
        uint4 aj = *(const uint4*)(xjxi + (size_t)se*128 + c8*8);
        uint4 ai = *(const uint4*)(xjxi + (size_t)node*128 + 64 + c8*8);
        uint4 ae = *(const uint4*)(eproj + (size_t)e*192 + c8*8);
        const unsigned short* pj = (const unsigned short*)&aj;
        const unsigned short* pi = (const unsigned short*)&ai;
        const unsigned short* pe = (const unsigned short*)&ae;
        #pragma unroll
        for (int j = 0; j < 8; ++j)
            s_xij[p][c8*8 + j] = b2f(pj[j]) + b2f(pi[j]) + b2f(pe[j]);
    }
    __syncthreads();
    {
        int p = t >> 4, q = t & 15;
        float dt = s_rhat[p][0]*s_rhat[q][0] + s_rhat[p][1]*s_rhat[q][1] + s_rhat[p][2]*s_rhat[q][2];
        s_c[p][q] = fminf(fmaxf(dt, -0.999999f), 0.999999f);
    }
    __syncthreads();
    if (t < 240) {
        int p  = t / 15;
        int qq = t - p*15;
        int q  = qq + (qq >= p ? 1 : 0);
        float c   = s_c[p][q];
        float c2  = 2.0f * c;
        float tk0 = 1.0f;
        float tk1 = c;
        float acc = 0.f;
        const float* xp = &s_xij[p][0];
        const float* xq = &s_xij[q][0];
        #pragma unroll
        for (int k0 = 0; k0 < 64; k0 += 4) {
            float4 xp4 = *(const float4*)(xp + k0);
            float4 xq4 = *(const float4*)(xq + k0);
            float4 a4  = *(const float4*)(&s_attn[k0]);
            float v0 = tk0 + xp4.x + xq4.x;
            acc = fmaf(a4.x, silu_f(v0), acc);
            { float tn2 = c2*tk1 - tk0; tk0 = tk1; tk1 = tn2; }
            float v1 = tk0 + xp4.y + xq4.y;
            acc = fmaf(a4.y, silu_f(v1), acc);
            { float tn2 = c2*tk1 - tk0; tk0 = tk1; tk1 = tn2; }
            float v2 = tk0 + xp4.z + xq4.z;
            acc = fmaf(a4.z, silu_f(v2), acc);
            { float tn2 = c2*tk1 - tk0; tk0 = tk1; tk1 = tn2; }
            float v3 = tk0 + xp4.w + xq4.w;
            acc = fmaf(a4.w, silu_f(v3), acc);
            { float tn2 = c2*tk1 - tk0; tk0 = tk1; tk1 = tn2; }
        }
        s_logit[p][q] = acc;
    }
    __syncthreads();
    if (t < 16) {
        int q = t;
        float mx = -1e30f;
        #pragma unroll
        for (int p = 0; p < 16; ++p) if (p != q) mx = fmaxf(mx, s_logit[p][q]);
        float ssum = 0.f;
        float ex[16];
        #pragma unroll
        for (int p = 0; p < 16; ++p) {
            float e = (p == q) ? 0.f : __expf(s_logit[p][q] - mx);
            ex[p] = e; ssum += e;
        }
        float inv = 1.0f / ssum;
        #pragma unroll
        for (int p = 0; p < 16; ++p) s_a[p][q] = ex[p] * inv;
    }
    __syncthreads();
    if (t < 16) {
        int p = t;
        float sw = 0.f;
        #pragma unroll
        for (int q = 0; q < 16; ++q) sw += s_a[p][q];
        s_w[p] = sw;
    }
    __syncthreads();
    if (t < 64) {
        float acc = 0.f;
        #pragma unroll
        for (int p = 0; p < 16; ++p) acc += s_w[p] * s_xij[p][t];
        xn[(size_t)node*64 + t] = f2b(acc);
    }
}

// ---------------- final: out = bfc + mean_i (x[i] . Wfc) ----------------
__global__ void init_out(float* __restrict__ out, const float* __restrict__ bfc) {
    out[0] = bfc[0];
}
__global__ __launch_bounds__(256) void reduce_kernel(const unsigned short* __restrict__ x,
    const float* __restrict__ Wfc, float* __restrict__ out) {
    __shared__ float s[256];
    int t = threadIdx.x;
    float local = 0.f;
    for (int i = blockIdx.x; i < N_NODES; i += gridDim.x) local += b2f(x[(size_t)i*D_MODEL + t]);
    local *= Wfc[t];
    s[t] = local; __syncthreads();
    for (int off = 128; off > 0; off >>= 1) {
        if (t < off) s[t] += s[t+off];
        __syncthreads();
    }
    if (t == 0) atomicAdd(out, s[0] * (1.0f/(float)N_NODES));
}

extern "C" void kernel_launch(void* const* d_in, const int* in_sizes, int n_in,
                              void* d_out, int out_size, void* d_ws, size_t ws_size,
                              hipStream_t stream) {
    (void)in_sizes; (void)n_in; (void)out_size; (void)ws_size;
    const float* r    = (const float*)d_in[0];
    const int*   an   = (const int*)  d_in[1];
    const int*   src  = (const int*)  d_in[2];
    const float* emb  = (const float*)d_in[6];
    const float* Wsrc = (const float*)d_in[7];
    const float* bsrc = (const float*)d_in[8];
    const float* Wdst = (const float*)d_in[9];
    const float* bdst = (const float*)d_in[10];
    const float* Wedge= (const float*)d_in[11];
    const float* bedge= (const float*)d_in[12];
    const float* attn = (const float*)d_in[13];
    const float* W1   = (const float*)d_in[14];
    const float* b1   = (const float*)d_in[15];
    const float* W2   = (const float*)d_in[16];
    const float* b2   = (const float*)d_in[17];
    const float* Wfc  = (const float*)d_in[18];
    const float* bfc  = (const float*)d_in[19];

    char* ws = (char*)d_ws;
    float* d_d              = (float*)(ws);                    // 384000 B
    float* d_rhat           = (float*)(ws + 384000);           // 1536000 B
    unsigned short* wbf     = (unsigned short*)(ws + 1920000); // 2260992 B
    unsigned short* d_x     = (unsigned short*)(ws + 4180992); // 3072000 B
    unsigned short* d_xjxi  = (unsigned short*)(ws + 7252992); // 1536000 B
    unsigned short* d_eproj = (unsigned short*)(ws + 8788992); // 36864000 B
    unsigned short* d_xn    = (unsigned short*)(ws + 45652992);// 768000 B
    unsigned short* d_h     = (unsigned short*)(ws + 46420992);// 12288000 B
    float* out = (float*)d_out;

    unsigned short* wsrc_bf  = wbf + WSRC_OFF;
    unsigned short* wdst_bf  = wbf + WDST_OFF;
    unsigned short* wedge_bf = wbf + WEDGE_OFF;
    unsigned short* w1_bf    = wbf + W1_OFF;
    unsigned short* w2_bf    = wbf + W2_OFF;

    cvt_weights<<<(WTOTAL+255)/256, 256, 0, stream>>>(Wsrc, Wdst, Wedge, W1, W2, wbf);
    embed_kernel<<<N_NODES, 256, 0, stream>>>(an, emb, d_x);
    geom_kernel<<<(N_EDGES+255)/256, 256, 0, stream>>>(r, d_d, d_rhat);
    // eproj for all 3 layers: [E,192] = RBF(d) @ Wedge^T + bedge
    mgemm<0,1,0><<<dim3(3,750), 256, 0, stream>>>(
        (const unsigned short*)nullptr, 0, wedge_bf, (const unsigned short*)nullptr, 256,
        bedge, (const float*)nullptr, d_eproj, 192, N_EDGES, 256, d_d);

    for (int l = 0; l < 3; ++l) {
        mgemm<0,0,1><<<dim3(2,47), 256, 0, stream>>>(
            d_x, 256, wsrc_bf + l*16384, wdst_bf + l*16384, 256,
            bsrc + l*64, bdst + l*64, d_xjxi, 128, N_NODES, 256, nullptr);
        angle_kernel<<<N_NODES, 256, 0, stream>>>(
            d_xjxi, d_eproj + l*64, d_rhat, src, attn + l*64, d_xn);
        mgemm<1,0,0><<<dim3(16,47), 256, 0, stream>>>(
            d_xn, 64, w1_bf + l*65536, (const unsigned short*)nullptr, 64,
            b1 + l*D_FF, (const float*)nullptr, d_h, D_FF, N_NODES, 64, nullptr);
        mgemm<0,0,0><<<dim3(4,47), 256, 0, stream>>>(
            d_h, 1024, w2_bf + l*262144, (const unsigned short*)nullptr, 1024,
            b2 + l*D_MODEL, (const float*)nullptr, d_x, D_MODEL, N_NODES, 1024, nullptr);
    }
    init_out<<<1, 1, 0, stream>>>(out, bfc);
    reduce_kernel<<<48, 256, 0, stream>>>(d_x, Wfc, out);
}

// Round 4
// 394.624 us; speedup vs baseline: 2.8086x; 1.0708x over previous
//
#include <hip/hip_runtime.h>

#define N_NODES 6000
#define DEG_    16
#define N_EDGES (N_NODES*DEG_)
#define D_MODEL 256
#define D_MSG   64
#define D_FF    1024

typedef __bf16 bf16x8 __attribute__((ext_vector_type(8)));
typedef float floatx4 __attribute__((ext_vector_type(4)));

__device__ __forceinline__ float silu_f(float v) {
    return v * __builtin_amdgcn_rcpf(1.0f + __expf(-v));
}
__device__ __forceinline__ float b2f(unsigned short u) {
    union { unsigned int i; float f; } v; v.i = ((unsigned int)u) << 16; return v.f;
}
__device__ __forceinline__ unsigned short f2b(float f) {
    union { float f; unsigned int i; } v; v.f = f;
    unsigned int r = (v.i + 0x7FFFu + ((v.i >> 16) & 1u)) >> 16;
    return (unsigned short)r;
}

// ---------------- fused prep: weight cvt + embed + geometry ----------------
#define WSRC_OFF 0
#define WDST_OFF 49152
#define WEDGE_OFF 98304
#define W1_OFF 147456
#define W2_OFF 344064
#define WTOTAL 1130496
#define CVT_BLOCKS ((WTOTAL+255)/256)          // 4416
#define GEOM_BLOCKS (N_EDGES/256)              // 375
__global__ __launch_bounds__(256) void prep_kernel(
    const float* __restrict__ Wsrc, const float* __restrict__ Wdst,
    const float* __restrict__ Wedge, const float* __restrict__ W1,
    const float* __restrict__ W2, unsigned short* __restrict__ wdst_out,
    const int* __restrict__ an, const float* __restrict__ emb,
    unsigned short* __restrict__ x,
    const float* __restrict__ r, float* __restrict__ d, float* __restrict__ rhat) {
    int b = blockIdx.x;
    int t = threadIdx.x;
    if (b < CVT_BLOCKS) {
        int i = b*256 + t;
        if (i < WTOTAL) {
            float v;
            if      (i < WDST_OFF)  v = Wsrc[i];
            else if (i < WEDGE_OFF) v = Wdst[i - WDST_OFF];
            else if (i < W1_OFF)    v = Wedge[i - WEDGE_OFF];
            else if (i < W2_OFF)    v = W1[i - W1_OFF];
            else                    v = W2[i - W2_OFF];
            wdst_out[i] = f2b(v);
        }
    } else if (b < CVT_BLOCKS + N_NODES) {
        int i = b - CVT_BLOCKS;
        x[i*D_MODEL + t] = f2b(emb[an[i]*D_MODEL + t]);
    } else {
        int e = (b - CVT_BLOCKS - N_NODES)*256 + t;
        float xx = r[e*3+0], yy = r[e*3+1], zz = r[e*3+2];
        float n = sqrtf(xx*xx + yy*yy + zz*zz);
        d[e] = n;
        float inv = 1.0f / n;
        *(float4*)(rhat + (size_t)e*4) = make_float4(xx*inv, yy*inv, zz*inv, 0.f);
    }
}

// ---------------- MFMA bf16 GEMM: C = bf16(act(A @ B^T + bias)) ----------------
// Block tile TMx64 (TM in {128,64}), 4 waves each (TM/4)x64, BK=32.
// DUALB: grid.x==2, col-block 0 -> B1/bias1, 1 -> B2/bias2 (64-row each).
#define APITCH 40
template<int ACT, int RBF, int DUALB, int TM>
__global__ __launch_bounds__(256) void mgemm(
    const unsigned short* __restrict__ A, int lda,
    const unsigned short* __restrict__ B1, const unsigned short* __restrict__ B2, int ldb,
    const float* __restrict__ bias1, const float* __restrict__ bias2,
    unsigned short* __restrict__ C, int ldc, int M, int K,
    const float* __restrict__ dvec) {
    constexpr int WR = TM/4;       // rows per wave
    constexpr int FC = WR/16;      // 16-row fragments per wave
    __shared__ __align__(16) unsigned short As[TM*APITCH];
    __shared__ __align__(16) unsigned short Bs[64*APITCH];
    const int t = threadIdx.x;
    const int w = t >> 6;
    const int lane = t & 63;
    const int lr = lane & 15;
    const int lq = lane >> 4;
    const int n0 = blockIdx.x * 64;
    const int m0 = blockIdx.y * TM;
    const unsigned short* B = B1;
    const float* bias = bias1;
    if (DUALB && blockIdx.x == 1) { B = B2; bias = bias2; }
    const unsigned short* Brow = DUALB ? B : (B + (size_t)n0*ldb);

    floatx4 acc[FC][4] = {};

    for (int k0 = 0; k0 < K; k0 += 32) {
        #pragma unroll
        for (int it = 0; it < TM/64; ++it) {
            int i = t + it*256;
            int row = i >> 2, chk = i & 3;
            int gm = m0 + row;
            uint4 val = make_uint4(0,0,0,0);
            if (RBF) {
                const float gamma = 31.875f;
                const float step  = 8.0f / 255.0f;
                float dv = dvec[gm];          // RBF path: M % TM == 0
                int kb = k0 + chk*8;
                unsigned short h[8];
                #pragma unroll
                for (int j = 0; j < 8; ++j) {
                    float tt = dv - (float)(kb+j) * step;
                    h[j] = f2b(__expf(-gamma * tt * tt));
                }
                val = *(uint4*)h;
            } else if (gm < M) {
                val = *(const uint4*)(A + (size_t)gm*lda + k0 + chk*8);
            }
            *(uint4*)(&As[row*APITCH + chk*8]) = val;
        }
        {
            int row = t >> 2, chk = t & 3;
            uint4 val = *(const uint4*)(Brow + (size_t)row*ldb + k0 + chk*8);
            *(uint4*)(&Bs[row*APITCH + chk*8]) = val;
        }
        __syncthreads();
        bf16x8 af[FC], bfr[4];
        #pragma unroll
        for (int fc = 0; fc < FC; ++fc)
            af[fc] = *(const bf16x8*)(&As[(w*WR + fc*16 + lr)*APITCH + lq*8]);
        #pragma unroll
        for (int ns = 0; ns < 4; ++ns)
            bfr[ns] = *(const bf16x8*)(&Bs[(ns*16 + lr)*APITCH + lq*8]);
        #pragma unroll
        for (int ns = 0; ns < 4; ++ns)
            #pragma unroll
            for (int fc = 0; fc < FC; ++fc)
                acc[fc][ns] = __builtin_amdgcn_mfma_f32_16x16x32_bf16(af[fc], bfr[ns], acc[fc][ns], 0,0,0);
        __syncthreads();
    }
    #pragma unroll
    for (int ns = 0; ns < 4; ++ns) {
        int bc = ns*16 + lr;
        float bv = bias[DUALB ? bc : (n0 + bc)];
        #pragma unroll
        for (int fc = 0; fc < FC; ++fc) {
            #pragma unroll
            for (int rg = 0; rg < 4; ++rg) {
                int gm = m0 + w*WR + fc*16 + lq*4 + rg;
                if (gm < M) {
                    float v = acc[fc][ns][rg] + bv;
                    if (ACT) v = silu_f(v);
                    C[(size_t)gm*ldc + n0 + bc] = f2b(v);
                }
            }
        }
    }
}

// ---------------- angle attention, one block per node (bf16 IO, fp32 math) ----------------
// Pair thread (p,q): logit = sum_k attn[k]*silu(T_k(c_pq) + xij[p][k] + xij[q][k]).
// attn read via wave-uniform global loads (scalarized to SGPRs); xij via ds_read_b128.
#define XSTRIDE 68
__global__ __launch_bounds__(256) void angle_kernel(
    const unsigned short* __restrict__ xjxi,   // [N,128] bf16: 0..63 xj, 64..127 xi
    const unsigned short* __restrict__ eproj,  // [E,192] bf16, pre-offset by l*64
    const float* __restrict__ rhat,            // [E,4]
    const int*   __restrict__ src,             // [E]
    const float* __restrict__ attn,            // [64] pre-offset, wave-uniform
    unsigned short* __restrict__ xn) {         // [N,64] bf16
    __shared__ __align__(16) float s_xij[16][XSTRIDE];
    __shared__ float s_rhat[16][4];
    __shared__ float s_logit[16][17];
    __shared__ float s_a[16][17];
    __shared__ float s_w[16];
    int node = blockIdx.x;
    int t = threadIdx.x;

    if (t < 16) {
        float4 rv = *(const float4*)(rhat + (size_t)(node*DEG_ + t)*4);
        s_rhat[t][0] = rv.x; s_rhat[t][1] = rv.y; s_rhat[t][2] = rv.z; s_rhat[t][3] = 0.f;
    }
    if (t < 128) {
        int p = t >> 3, c8 = t & 7;
        int e = node*DEG_ + p;
        int se = src[e];
        uint4 aj = *(const uint4*)(xjxi + (size_t)se*128 + c8*8);
        uint4 ai = *(const uint4*)(xjxi + (size_t)node*128 + 64 + c8*8);
        uint4 ae = *(const uint4*)(eproj + (size_t)e*192 + c8*8);
        const unsigned short* pj = (const unsigned short*)&aj;
        const unsigned short* pi = (const unsigned short*)&ai;
        const unsigned short* pe = (const unsigned short*)&ae;
        #pragma unroll
        for (int j = 0; j < 8; ++j)
            s_xij[p][c8*8 + j] = b2f(pj[j]) + b2f(pi[j]) + b2f(pe[j]);
    }
    __syncthreads();
    if (t < 240) {
        int p  = t / 15;
        int qq = t - p*15;
        int q  = qq + (qq >= p ? 1 : 0);
        float c = s_rhat[p][0]*s_rhat[q][0] + s_rhat[p][1]*s_rhat[q][1] + s_rhat[p][2]*s_rhat[q][2];
        c = fminf(fmaxf(c, -0.999999f), 0.999999f);
        float c2  = 2.0f * c;
        float tk0 = 1.0f;
        float tk1 = c;
        float acc = 0.f;
        const float* xp = &s_xij[p][0];
        const float* xq = &s_xij[q][0];
        #pragma unroll
        for (int k0 = 0; k0 < 64; k0 += 4) {
            float4 xp4 = *(const float4*)(xp + k0);
            float4 xq4 = *(const float4*)(xq + k0);
            float a0 = attn[k0+0], a1 = attn[k0+1], a2 = attn[k0+2], a3 = attn[k0+3];
            float v0 = tk0 + xp4.x + xq4.x;
            acc = fmaf(a0, silu_f(v0), acc);
            { float tn2 = c2*tk1 - tk0; tk0 = tk1; tk1 = tn2; }
            float v1 = tk0 + xp4.y + xq4.y;
            acc = fmaf(a1, silu_f(v1), acc);
            { float tn2 = c2*tk1 - tk0; tk0 = tk1; tk1 = tn2; }
            float v2 = tk0 + xp4.z + xq4.z;
            acc = fmaf(a2, silu_f(v2), acc);
            { float tn2 = c2*tk1 - tk0; tk0 = tk1; tk1 = tn2; }
            float v3 = tk0 + xp4.w + xq4.w;
            acc = fmaf(a3, silu_f(v3), acc);
            { float tn2 = c2*tk1 - tk0; tk0 = tk1; tk1 = tn2; }
        }
        s_logit[p][q] = acc;
    }
    __syncthreads();
    if (t < 16) {
        int q = t;
        float mx = -1e30f;
        #pragma unroll
        for (int p = 0; p < 16; ++p) if (p != q) mx = fmaxf(mx, s_logit[p][q]);
        float ssum = 0.f;
        float ex[16];
        #pragma unroll
        for (int p = 0; p < 16; ++p) {
            float e = (p == q) ? 0.f : __expf(s_logit[p][q] - mx);
            ex[p] = e; ssum += e;
        }
        float inv = 1.0f / ssum;
        #pragma unroll
        for (int p = 0; p < 16; ++p) s_a[p][q] = ex[p] * inv;
    }
    __syncthreads();
    if (t < 16) {
        int p = t;
        float sw = 0.f;
        #pragma unroll
        for (int q = 0; q < 16; ++q) sw += s_a[p][q];
        s_w[p] = sw;
    }
    __syncthreads();
    if (t < 64) {
        float acc = 0.f;
        #pragma unroll
        for (int p = 0; p < 16; ++p) acc += s_w[p] * s_xij[p][t];
        xn[(size_t)node*64 + t] = f2b(acc);
    }
}

// ---------------- final: out = bfc + mean_i (x[i] . Wfc) ----------------
__global__ void init_out(float* __restrict__ out, const float* __restrict__ bfc) {
    out[0] = bfc[0];
}
__global__ __launch_bounds__(256) void reduce_kernel(const unsigned short* __restrict__ x,
    const float* __restrict__ Wfc, float* __restrict__ out) {
    __shared__ float s[256];
    int t = threadIdx.x;
    float local = 0.f;
    for (int i = blockIdx.x; i < N_NODES; i += gridDim.x) local += b2f(x[(size_t)i*D_MODEL + t]);
    local *= Wfc[t];
    s[t] = local; __syncthreads();
    for (int off = 128; off > 0; off >>= 1) {
        if (t < off) s[t] += s[t+off];
        __syncthreads();
    }
    if (t == 0) atomicAdd(out, s[0] * (1.0f/(float)N_NODES));
}

extern "C" void kernel_launch(void* const* d_in, const int* in_sizes, int n_in,
                              void* d_out, int out_size, void* d_ws, size_t ws_size,
                              hipStream_t stream) {
    (void)in_sizes; (void)n_in; (void)out_size; (void)ws_size;
    const float* r    = (const float*)d_in[0];
    const int*   an   = (const int*)  d_in[1];
    const int*   src  = (const int*)  d_in[2];
    const float* emb  = (const float*)d_in[6];
    const float* Wsrc = (const float*)d_in[7];
    const float* bsrc = (const float*)d_in[8];
    const float* Wdst = (const float*)d_in[9];
    const float* bdst = (const float*)d_in[10];
    const float* Wedge= (const float*)d_in[11];
    const float* bedge= (const float*)d_in[12];
    const float* attn = (const float*)d_in[13];
    const float* W1   = (const float*)d_in[14];
    const float* b1   = (const float*)d_in[15];
    const float* W2   = (const float*)d_in[16];
    const float* b2   = (const float*)d_in[17];
    const float* Wfc  = (const float*)d_in[18];
    const float* bfc  = (const float*)d_in[19];

    char* ws = (char*)d_ws;
    float* d_d              = (float*)(ws);                    // 384000 B
    float* d_rhat           = (float*)(ws + 384000);           // 1536000 B
    unsigned short* wbf     = (unsigned short*)(ws + 1920000); // 2260992 B
    unsigned short* d_x     = (unsigned short*)(ws + 4180992); // 3072000 B
    unsigned short* d_xjxi  = (unsigned short*)(ws + 7252992); // 1536000 B
    unsigned short* d_eproj = (unsigned short*)(ws + 8788992); // 36864000 B
    unsigned short* d_xn    = (unsigned short*)(ws + 45652992);// 768000 B
    unsigned short* d_h     = (unsigned short*)(ws + 46420992);// 12288000 B
    float* out = (float*)d_out;

    unsigned short* wsrc_bf  = wbf + WSRC_OFF;
    unsigned short* wdst_bf  = wbf + WDST_OFF;
    unsigned short* wedge_bf = wbf + WEDGE_OFF;
    unsigned short* w1_bf    = wbf + W1_OFF;
    unsigned short* w2_bf    = wbf + W2_OFF;

    prep_kernel<<<CVT_BLOCKS + N_NODES + GEOM_BLOCKS, 256, 0, stream>>>(
        Wsrc, Wdst, Wedge, W1, W2, wbf, an, emb, d_x, r, d_d, d_rhat);
    // eproj for all 3 layers: [E,192] = RBF(d) @ Wedge^T + bedge
    mgemm<0,1,0,128><<<dim3(3,750), 256, 0, stream>>>(
        (const unsigned short*)nullptr, 0, wedge_bf, (const unsigned short*)nullptr, 256,
        bedge, (const float*)nullptr, d_eproj, 192, N_EDGES, 256, d_d);

    for (int l = 0; l < 3; ++l) {
        mgemm<0,0,1,64><<<dim3(2,94), 256, 0, stream>>>(
            d_x, 256, wsrc_bf + l*16384, wdst_bf + l*16384, 256,
            bsrc + l*64, bdst + l*64, d_xjxi, 128, N_NODES, 256, nullptr);
        angle_kernel<<<N_NODES, 256, 0, stream>>>(
            d_xjxi, d_eproj + l*64, d_rhat, src, attn + l*64, d_xn);
        mgemm<1,0,0,64><<<dim3(16,94), 256, 0, stream>>>(
            d_xn, 64, w1_bf + l*65536, (const unsigned short*)nullptr, 64,
            b1 + l*D_FF, (const float*)nullptr, d_h, D_FF, N_NODES, 64, nullptr);
        mgemm<0,0,0,64><<<dim3(4,94), 256, 0, stream>>>(
            d_h, 1024, w2_bf + l*262144, (const unsigned short*)nullptr, 1024,
            b2 + l*D_MODEL, (const float*)nullptr, d_x, D_MODEL, N_NODES, 1024, nullptr);
    }
    init_out<<<1, 1, 0, stream>>>(out, bfc);
    reduce_kernel<<<48, 256, 0, stream>>>(d_x, Wfc, out);
}